// Round 1
// baseline (884.071 us; speedup 1.0000x reference)
//
#include <hip/hip_runtime.h>
#include <math.h>

// N=20000, K=63, D=50, E=300
// out[n] = Wr . elu( Wg @ (sum_k s[n,k]*texts[n,k]) + g_bias ) + br
// texts = [neighbor_embs (63), node (1)]; node = q^T Wbil ent + bbil; ent = entity@Wp^T + bp

// ---------------- Kernel A: ent + bilinear -> node_ws [N,50] ----------------
// 32 nodes per block, 256 threads, 625 blocks (20000 = 625*32 exactly).
__global__ __launch_bounds__(256) void kernelA(
    const float* __restrict__ q,      // [N,50]
    const float* __restrict__ entity, // [N,300]
    const float* __restrict__ Wp,     // [50,300]
    const float* __restrict__ bp,     // [50]
    const float* __restrict__ Wbil,   // [50,50,50]  (o,i,j)
    const float* __restrict__ bbil,   // [50]
    float* __restrict__ node_ws)      // [N,50]
{
    __shared__ float qs[32 * 50];     // q tile, row-major [n][i]
    __shared__ float entsT[50 * 32];  // ent tile transposed [j][n]
    __shared__ float Bs[51 * 52];     // Wbil i-slice transposed [j][o], padded rows + slack row

    const int tid = threadIdx.x;
    const int n0 = blockIdx.x * 32;

    // q tile: 32 full rows are contiguous -> coalesced copy of 1600 floats
    for (int idx = tid; idx < 1600; idx += 256)
        qs[idx] = q[(size_t)n0 * 50 + idx];

    // ent phase: ent[n][d] = bp[d] + entity[n,:] . Wp[d,:]
    // lanes share n (broadcast entity), span d (Wp lines L1-hot within tight e-window)
    for (int idx = tid; idx < 1600; idx += 256) {
        int nl = idx / 50, d = idx - nl * 50;
        const float* er = entity + (size_t)(n0 + nl) * 300;
        const float* wr = Wp + d * 300;
        float s = bp[d];
        #pragma unroll 4
        for (int e = 0; e < 300; ++e) s += er[e] * wr[e];
        entsT[d * 32 + nl] = s;
    }

    // bilinear GEMM: node[n][o] = sum_i q[n,i] * ( sum_j Wbil[o,i,j] * ent[n,j] )
    const int tx = tid & 15, ty = tid >> 4;  // tx -> o (4 each), ty -> n (2 each)
    float acc[2][4] = {};
    for (int i = 0; i < 50; ++i) {
        __syncthreads();  // previous j-loop done (and, at i=0, ent phase done)
        // stage Wbil[:, i, :] transposed into Bs[j][o]
        for (int idx = tid; idx < 2500; idx += 256) {
            int o = idx / 50, j = idx - o * 50;
            Bs[j * 52 + o] = Wbil[o * 2500 + i * 50 + j];
        }
        __syncthreads();
        const float q0 = qs[(ty * 2) * 50 + i];
        const float q1 = qs[(ty * 2 + 1) * 50 + i];
        #pragma unroll 5
        for (int j = 0; j < 50; ++j) {
            const float2 e2 = *(const float2*)&entsT[j * 32 + ty * 2];
            const float4 b4 = *(const float4*)&Bs[j * 52 + tx * 4];
            const float a0 = q0 * e2.x, a1 = q1 * e2.y;
            acc[0][0] += a0 * b4.x; acc[0][1] += a0 * b4.y;
            acc[0][2] += a0 * b4.z; acc[0][3] += a0 * b4.w;
            acc[1][0] += a1 * b4.x; acc[1][1] += a1 * b4.y;
            acc[1][2] += a1 * b4.z; acc[1][3] += a1 * b4.w;
        }
    }
    #pragma unroll
    for (int a = 0; a < 2; ++a) {
        const int n = n0 + ty * 2 + a;
        #pragma unroll
        for (int b = 0; b < 4; ++b) {
            const int o = tx * 4 + b;
            if (o < 50) node_ws[(size_t)n * 50 + o] = acc[a][b] + bbil[o];
        }
    }
}

// ---------------- Kernel B: weighted neighbor sum + Wg + ELU + head ----------------
// 4 nodes per block (one per wave), 256 threads, 5000 blocks.
__global__ __launch_bounds__(256) void kernelB(
    const float* __restrict__ nb,      // [N,63,50]
    const float* __restrict__ scores,  // [N,64]
    const float* __restrict__ node_ws, // [N,50]
    const float* __restrict__ Wg,      // [50,50] (o,d)
    const float* __restrict__ g_bias,  // [50]
    const float* __restrict__ Wr,      // [1,50]
    const float* __restrict__ br,      // [1]
    float* __restrict__ out)           // [N]
{
    __shared__ float buf[4 * 3150];    // 4 neighbor rows (63*50 each)
    __shared__ float sc[4 * 64];
    __shared__ float tvec[4 * 50];

    const int tid = threadIdx.x;
    const int n0 = blockIdx.x * 4;

    sc[tid] = scores[(size_t)n0 * 64 + tid];  // 256 == 4*64, coalesced
    // stage 4*3150 floats as float2, fully coalesced
    for (int idx = tid; idx < 6300; idx += 256) {
        int nodeIdx = idx / 1575, pos = idx - nodeIdx * 1575;
        const float2 v = *(const float2*)(nb + (size_t)(n0 + nodeIdx) * 3150 + 2 * pos);
        *(float2*)(buf + nodeIdx * 3150 + 2 * pos) = v;
    }
    __syncthreads();

    const int w = tid >> 6, lane = tid & 63;
    const int n = n0 + w;
    if (lane < 50) {
        // t[d] = s[63]*node[d] + sum_k s[k]*nb[k][d]
        float t = sc[w * 64 + 63] * node_ws[(size_t)n * 50 + lane];
        const float* bw = buf + w * 3150 + lane;
        #pragma unroll 7
        for (int k = 0; k < 63; ++k) t += sc[w * 64 + k] * bw[k * 50];
        tvec[w * 50 + lane] = t;
    }
    __syncthreads();
    float p = 0.f;
    if (lane < 50) {
        float a = g_bias[lane];
        const float* wg = Wg + lane * 50;
        const float* tv = tvec + w * 50;
        #pragma unroll 5
        for (int d = 0; d < 50; ++d) a += wg[d] * tv[d];
        const float f = a > 0.f ? a : (expf(a) - 1.f);
        p = f * Wr[lane];
    }
    #pragma unroll
    for (int off = 32; off > 0; off >>= 1) p += __shfl_down(p, off);
    if (lane == 0) out[n] = p + br[0];
}

extern "C" void kernel_launch(void* const* d_in, const int* in_sizes, int n_in,
                              void* d_out, int out_size, void* d_ws, size_t ws_size,
                              hipStream_t stream) {
    const float* q_   = (const float*)d_in[0];
    const float* ent  = (const float*)d_in[1];
    const float* nb   = (const float*)d_in[2];
    const float* scr  = (const float*)d_in[3];
    const float* Wp   = (const float*)d_in[4];
    const float* bp   = (const float*)d_in[5];
    const float* Wb   = (const float*)d_in[6];
    const float* bb   = (const float*)d_in[7];
    const float* Wg   = (const float*)d_in[8];
    const float* gb   = (const float*)d_in[9];
    const float* Wr   = (const float*)d_in[10];
    const float* br   = (const float*)d_in[11];
    float* out = (float*)d_out;
    float* node_ws = (float*)d_ws;  // needs N*50*4 = 4 MB of ws

    hipLaunchKernelGGL(kernelA, dim3(625), dim3(256), 0, stream,
                       q_, ent, Wp, bp, Wb, bb, node_ws);
    hipLaunchKernelGGL(kernelB, dim3(5000), dim3(256), 0, stream,
                       nb, scr, node_ws, Wg, gb, Wr, br, out);
}

// Round 2
// 567.902 us; speedup vs baseline: 1.5567x; 1.5567x over previous
//
#include <hip/hip_runtime.h>
#include <math.h>

// N=20000, K=63, D=50, E=300
// ws layout (floats): Wt[125000] | ent_ws[1000000] | part[2][20000*50]
#define NNODES 20000

// ---------- A0t: transpose Wbil[o,i,j] -> Wt[k=i*50+j][o] (500 KB) ----------
__global__ __launch_bounds__(256) void kA0t(const float* __restrict__ Wbil,
                                            float* __restrict__ Wt) {
    for (int idx = blockIdx.x * 256 + threadIdx.x; idx < 125000; idx += gridDim.x * 256) {
        int o = idx / 2500, k = idx - o * 2500;
        Wt[k * 50 + o] = Wbil[idx];
    }
}

// ---------- A0e: ent[n,d] = entity[n,:]@Wp[d,:] + bp[d], LDS-tiled ----------
// 32 nodes/block, 625 blocks. K=300 in 6 chunks of 50.
__global__ __launch_bounds__(256) void kA0e(const float* __restrict__ entity,
                                            const float* __restrict__ Wp,
                                            const float* __restrict__ bp,
                                            float* __restrict__ ent_ws) {
    __shared__ float esT[50 * 34];       // [ee][nl], stride 34 (2-way = free)
    __shared__ float Ws[50 * 52 + 16];   // [ee][d],  stride 52 + slack for tx=15 float4
    const int tid = threadIdx.x;
    const int n0 = blockIdx.x * 32;
    const int tx = tid & 15, ty = tid >> 4;  // tx -> 4 d's, ty -> 2 nodes
    const int ty2 = ty * 2;
    float acc[2][4] = {};

    for (int e0 = 0; e0 < 300; e0 += 50) {
        __syncthreads();
        for (int idx = tid; idx < 1600; idx += 256) {
            int nl = idx / 50, ee = idx - nl * 50;
            esT[ee * 34 + nl] = entity[(size_t)(n0 + nl) * 300 + e0 + ee];
        }
        for (int idx = tid; idx < 2500; idx += 256) {
            int d = idx / 50, ee = idx - d * 50;
            Ws[ee * 52 + d] = Wp[d * 300 + e0 + ee];  // 200B-run reads; write conflicts tiny vs compute
        }
        __syncthreads();
        #pragma unroll 10
        for (int ee = 0; ee < 50; ++ee) {
            const float2 e2 = *(const float2*)&esT[ee * 34 + ty2];
            const float4 b4 = *(const float4*)&Ws[ee * 52 + tx * 4];
            acc[0][0] += e2.x * b4.x; acc[0][1] += e2.x * b4.y;
            acc[0][2] += e2.x * b4.z; acc[0][3] += e2.x * b4.w;
            acc[1][0] += e2.y * b4.x; acc[1][1] += e2.y * b4.y;
            acc[1][2] += e2.y * b4.z; acc[1][3] += e2.y * b4.w;
        }
    }
    #pragma unroll
    for (int a = 0; a < 2; ++a) {
        const int n = n0 + ty2 + a;
        #pragma unroll
        for (int b = 0; b < 4; ++b) {
            const int d = tx * 4 + b;
            if (d < 50) ent_ws[(size_t)n * 50 + d] = acc[a][b] + bp[d];
        }
    }
}

// ---------- A1: bilinear, split-K=2, software-pipelined W staging ----------
// 32 nodes/block; h = bid&1 covers i in [h*25, h*25+25). 1250 blocks.
__global__ __launch_bounds__(256) void kA1(const float* __restrict__ q,
                                           const float* __restrict__ ent_ws,
                                           const float* __restrict__ Wt,
                                           float* __restrict__ part) {
    __shared__ float entsT[50 * 34];          // [j][nl]
    __shared__ float qs[32 * 25];             // [nl][ii]
    __shared__ float Bs[2][50 * 52 + 16];     // [j][o] double-buffered

    const int tid = threadIdx.x;
    const int h = blockIdx.x & 1;
    const int n0 = (blockIdx.x >> 1) * 32;
    const int i0 = h * 25;
    const int tx = tid & 15, ty = tid >> 4;
    const int ty2 = ty * 2;

    for (int idx = tid; idx < 1600; idx += 256) {
        int nl = idx / 50, d = idx - nl * 50;
        entsT[d * 34 + nl] = ent_ws[(size_t)(n0 + nl) * 50 + d];
    }
    for (int idx = tid; idx < 800; idx += 256) {
        int nl = idx / 25, ii = idx - nl * 25;
        qs[nl * 25 + ii] = q[(size_t)(n0 + nl) * 50 + i0 + ii];
    }
    // prologue: stage slice ii=0 into Bs[0]
    {
        const float* src = Wt + (size_t)i0 * 2500;
        float st[10];
        #pragma unroll
        for (int t = 0; t < 10; ++t) { int x = tid + t * 256; st[t] = (x < 2500) ? src[x] : 0.f; }
        #pragma unroll
        for (int t = 0; t < 10; ++t) {
            int x = tid + t * 256;
            if (x < 2500) { int j = x / 50, o = x - j * 50; Bs[0][j * 52 + o] = st[t]; }
        }
    }
    __syncthreads();

    float acc[2][4] = {};
    for (int ii = 0; ii < 25; ++ii) {
        const int cur = ii & 1;
        // prefetch next W slice into registers (overlaps with compute below)
        float pf[10];
        if (ii + 1 < 25) {
            const float* src = Wt + (size_t)(i0 + ii + 1) * 2500;
            #pragma unroll
            for (int t = 0; t < 10; ++t) { int x = tid + t * 256; if (x < 2500) pf[t] = src[x]; }
        }
        const float q0 = qs[ty2 * 25 + ii];
        const float q1 = qs[(ty2 + 1) * 25 + ii];
        const float* B = &Bs[cur][0];
        #pragma unroll 10
        for (int j = 0; j < 50; ++j) {
            const float2 e2 = *(const float2*)&entsT[j * 34 + ty2];
            const float4 b4 = *(const float4*)&B[j * 52 + tx * 4];
            const float a0 = q0 * e2.x, a1 = q1 * e2.y;
            acc[0][0] += a0 * b4.x; acc[0][1] += a0 * b4.y;
            acc[0][2] += a0 * b4.z; acc[0][3] += a0 * b4.w;
            acc[1][0] += a1 * b4.x; acc[1][1] += a1 * b4.y;
            acc[1][2] += a1 * b4.z; acc[1][3] += a1 * b4.w;
        }
        if (ii + 1 < 25) {
            float* Bn = &Bs[cur ^ 1][0];
            #pragma unroll
            for (int t = 0; t < 10; ++t) {
                int x = tid + t * 256;
                if (x < 2500) { int j = x / 50, o = x - j * 50; Bn[j * 52 + o] = pf[t]; }
            }
        }
        __syncthreads();
    }
    #pragma unroll
    for (int a = 0; a < 2; ++a) {
        const int n = n0 + ty2 + a;
        #pragma unroll
        for (int b = 0; b < 4; ++b) {
            const int o = tx * 4 + b;
            if (o < 50) part[((size_t)h * NNODES + n) * 50 + o] = acc[a][b];
        }
    }
}

// ---------- B: weighted neighbor sum + Wg matvec + ELU + rank head ----------
// wave-per-node, no neighbor staging. 4 nodes/block, 5000 blocks.
__global__ __launch_bounds__(256) void kB(const float* __restrict__ nb,
                                          const float* __restrict__ scores,
                                          const float* __restrict__ part,
                                          const float* __restrict__ bbil,
                                          const float* __restrict__ Wg,
                                          const float* __restrict__ g_bias,
                                          const float* __restrict__ Wr,
                                          const float* __restrict__ br,
                                          float* __restrict__ out) {
    __shared__ float Wgs[50 * 51];   // [o][d], stride 51 (odd -> conflict-free row reads)
    __shared__ float scs[256];
    __shared__ float tv[4][64];

    const int tid = threadIdx.x;
    const int n0 = blockIdx.x * 4;
    for (int idx = tid; idx < 2500; idx += 256) {
        int o = idx / 50, d = idx - o * 50;
        Wgs[o * 51 + d] = Wg[idx];
    }
    scs[tid] = scores[(size_t)n0 * 64 + tid];
    __syncthreads();

    const int w = tid >> 6, lane = tid & 63;
    const int n = n0 + w;
    if (lane < 50) {
        const float* base = nb + (size_t)n * 3150 + lane;
        const float* sw = &scs[w * 64];
        float tacc = 0.f;
        #pragma unroll 21
        for (int k = 0; k < 63; ++k) tacc += sw[k] * base[k * 50];
        const float nodev = part[(size_t)n * 50 + lane]
                          + part[((size_t)NNODES + n) * 50 + lane]
                          + bbil[lane];
        tv[w][lane] = tacc + sw[63] * nodev;
    }
    __syncthreads();

    float p = 0.f;
    if (lane < 50) {
        float a = g_bias[lane];
        const float* wrow = &Wgs[lane * 51];
        const float* twv = &tv[w][0];
        #pragma unroll 10
        for (int d = 0; d < 50; ++d) a += wrow[d] * twv[d];
        const float f = a > 0.f ? a : (__expf(a) - 1.f);
        p = f * Wr[lane];
    }
    #pragma unroll
    for (int off = 32; off; off >>= 1) p += __shfl_down(p, off);
    if (lane == 0) out[n] = p + br[0];
}

extern "C" void kernel_launch(void* const* d_in, const int* in_sizes, int n_in,
                              void* d_out, int out_size, void* d_ws, size_t ws_size,
                              hipStream_t stream) {
    const float* q_   = (const float*)d_in[0];
    const float* ent  = (const float*)d_in[1];
    const float* nb   = (const float*)d_in[2];
    const float* scr  = (const float*)d_in[3];
    const float* Wp   = (const float*)d_in[4];
    const float* bp   = (const float*)d_in[5];
    const float* Wb   = (const float*)d_in[6];
    const float* bb   = (const float*)d_in[7];
    const float* Wg   = (const float*)d_in[8];
    const float* gb   = (const float*)d_in[9];
    const float* Wr   = (const float*)d_in[10];
    const float* br   = (const float*)d_in[11];
    float* out = (float*)d_out;

    float* ws = (float*)d_ws;           // 12.5 MB total
    float* Wt      = ws;                // 125000
    float* ent_ws  = ws + 125000;       // 1,000,000
    float* part    = ws + 1125000;      // 2,000,000

    hipLaunchKernelGGL(kA0t, dim3(128),  dim3(256), 0, stream, Wb, Wt);
    hipLaunchKernelGGL(kA0e, dim3(625),  dim3(256), 0, stream, ent, Wp, bp, ent_ws);
    hipLaunchKernelGGL(kA1,  dim3(1250), dim3(256), 0, stream, q_, ent_ws, Wt, part);
    hipLaunchKernelGGL(kB,   dim3(5000), dim3(256), 0, stream, nb, scr, part, bb, Wg, gb, Wr, br, out);
}

// Round 3
// 454.750 us; speedup vs baseline: 1.9441x; 1.2488x over previous
//
#include <hip/hip_runtime.h>
#include <math.h>

#define NN 20000
typedef unsigned int uint;
typedef unsigned short ushort;
typedef __attribute__((ext_vector_type(8))) short bf16x8;
typedef __attribute__((ext_vector_type(4))) float f32x4;

__device__ __forceinline__ ushort f2b(float x) {
    uint u = __float_as_uint(x);
    return (ushort)((u + 0x7FFFu + ((u >> 16) & 1u)) >> 16);  // RNE
}
__device__ __forceinline__ float b2f(ushort b) {
    return __uint_as_float(((uint)b) << 16);
}

// ---------- Prep: zero-padded bf16 weights ----------
// WtT[o][k] (64 x 2560) = Wbil[o][k] (native [o][i*50+j] layout!), WpB[d][e] (64 x 384) = Wp
__global__ __launch_bounds__(256) void kPrep(const float* __restrict__ Wbil,
                                             const float* __restrict__ Wp,
                                             ushort* __restrict__ WtT,
                                             ushort* __restrict__ WpB) {
    const int stride = gridDim.x * 256;
    for (int i = blockIdx.x * 256 + threadIdx.x; i < 64 * 2560; i += stride) {
        int o = i / 2560, k = i - o * 2560;
        WtT[i] = (o < 50 && k < 2500) ? f2b(Wbil[o * 2500 + k]) : (ushort)0;
    }
    for (int i = blockIdx.x * 256 + threadIdx.x; i < 64 * 384; i += stride) {
        int d = i / 384, e = i - d * 384;
        WpB[i] = (d < 50 && e < 300) ? f2b(Wp[d * 300 + e]) : (ushort)0;
    }
}

// ---------- Main: fused ent-GEMM + bilinear-GEMM via bf16 MFMA ----------
// 64 nodes/block, split-K=2 over bilinear K=2560. 626 blocks, 256 threads (4 waves).
// Wave w: M-tile = nodes [w*16, w*16+16), N = 64 (4 tiles of 16).
__global__ __launch_bounds__(256) void kMain(
    const float* __restrict__ q,       // [N,50]
    const float* __restrict__ entity,  // [N,300]
    const float* __restrict__ bp,      // [50]
    const ushort* __restrict__ WpB,    // [64][384] bf16
    const ushort* __restrict__ WtT,    // [64][2560] bf16
    float* __restrict__ part)          // [2][NN][64]
{
    __shared__ ushort qs[64 * 50];     // bf16 q tile
    __shared__ ushort es[64 * 50];     // bf16 ent tile
    __shared__ ushort Xs[64 * 136];    // A tile [node][k], row stride 136
    __shared__ ushort Bs[64 * 136];    // B tile [col][k], row stride 136

    const int tid = threadIdx.x;
    const int h = blockIdx.x & 1;
    const int n0 = (blockIdx.x >> 1) * 64;
    const int w = tid >> 6, lane = tid & 63;
    const int c = lane & 15, quad = lane >> 4;
    const int nl = tid >> 2;           // staging row 0..63
    const int kc = (tid & 3) * 32;     // staging col chunk

    // stage q tile as bf16 (used in phase 1)
    for (int i = tid; i < 3200; i += 256) {
        int r = i / 50, d = i - r * 50;
        float v = (n0 + r < NN) ? q[(size_t)(n0 + r) * 50 + d] : 0.f;
        qs[i] = f2b(v);
    }

    // ---- phase 0: ent[64,50] = entity[64,300] @ WpB^T, K padded to 384 ----
    f32x4 accE[4] = {{0.f,0.f,0.f,0.f},{0.f,0.f,0.f,0.f},{0.f,0.f,0.f,0.f},{0.f,0.f,0.f,0.f}};
    for (int t = 0; t < 3; ++t) {
        const int e0 = t * 128;
        __syncthreads();
        // stage entity -> Xs (bf16), guarded
        {
            const int node = n0 + nl;
            uint pk[16];
            #pragma unroll
            for (int u8 = 0; u8 < 8; ++u8) {
                const int e = e0 + kc + u8 * 4;
                float4 v = make_float4(0.f, 0.f, 0.f, 0.f);
                if (node < NN) {
                    if (e + 3 < 300) v = *(const float4*)(entity + (size_t)node * 300 + e);
                    else {
                        if (e < 300)     v.x = entity[(size_t)node * 300 + e];
                        if (e + 1 < 300) v.y = entity[(size_t)node * 300 + e + 1];
                        if (e + 2 < 300) v.z = entity[(size_t)node * 300 + e + 2];
                    }
                }
                pk[u8 * 2]     = (uint)f2b(v.x) | ((uint)f2b(v.y) << 16);
                pk[u8 * 2 + 1] = (uint)f2b(v.z) | ((uint)f2b(v.w) << 16);
            }
            uint4* dst = (uint4*)(Xs + nl * 136 + kc);
            #pragma unroll
            for (int m = 0; m < 4; ++m)
                dst[m] = make_uint4(pk[m*4], pk[m*4+1], pk[m*4+2], pk[m*4+3]);
        }
        // stage WpB tile -> Bs
        {
            const uint4* src = (const uint4*)(WpB + nl * 384 + e0 + kc);
            uint4 v0 = src[0], v1 = src[1], v2 = src[2], v3 = src[3];
            uint4* dst = (uint4*)(Bs + nl * 136 + kc);
            dst[0] = v0; dst[1] = v1; dst[2] = v2; dst[3] = v3;
        }
        __syncthreads();
        #pragma unroll
        for (int ks = 0; ks < 4; ++ks) {
            bf16x8 a = *(const bf16x8*)(Xs + (w * 16 + c) * 136 + ks * 32 + quad * 8);
            #pragma unroll
            for (int nt = 0; nt < 4; ++nt) {
                bf16x8 b = *(const bf16x8*)(Bs + (nt * 16 + c) * 136 + ks * 32 + quad * 8);
                accE[nt] = __builtin_amdgcn_mfma_f32_16x16x32_bf16(a, b, accE[nt], 0, 0, 0);
            }
        }
    }
    // write ent (+bp) as bf16 into es; D layout: row=quad*4+r, col=lane&15
    #pragma unroll
    for (int nt = 0; nt < 4; ++nt) {
        const int d = nt * 16 + c;
        if (d < 50) {
            const float bpd = bp[d];
            #pragma unroll
            for (int r = 0; r < 4; ++r) {
                const int node = w * 16 + quad * 4 + r;
                es[node * 50 + d] = f2b(accE[nt][r] + bpd);
            }
        }
    }

    // ---- phase 1: bilinear, K-half [h*1280, h*1280+1280), 10 tiles of 128 ----
    f32x4 acc[4] = {{0.f,0.f,0.f,0.f},{0.f,0.f,0.f,0.f},{0.f,0.f,0.f,0.f},{0.f,0.f,0.f,0.f}};
    const int kb0 = h * 1280;
    for (int t = 0; t < 10; ++t) {
        const int kbase = kb0 + t * 128;
        __syncthreads();   // protects es (first iter) and Xs/Bs (later iters)
        // stage WtT tile -> Bs
        {
            const uint4* src = (const uint4*)(WtT + nl * 2560 + kbase + kc);
            uint4 v0 = src[0], v1 = src[1], v2 = src[2], v3 = src[3];
            uint4* dst = (uint4*)(Bs + nl * 136 + kc);
            dst[0] = v0; dst[1] = v1; dst[2] = v2; dst[3] = v3;
        }
        // form X tile: X[nl][k] = q[nl][k/50] * ent[nl][k%50] (padding handled by B=0)
        {
            int kg = kbase + kc;
            int i = kg / 50, j = kg - i * 50;
            const ushort* qsr = qs + nl * 50;
            const ushort* esr = es + nl * 50;
            float qv = b2f(qsr[i < 49 ? i : 49]);
            uint pk[16];
            #pragma unroll
            for (int u2 = 0; u2 < 16; ++u2) {
                ushort lo = f2b(qv * b2f(esr[j]));
                if (++j == 50) { j = 0; ++i; qv = b2f(qsr[i < 49 ? i : 49]); }
                ushort hi = f2b(qv * b2f(esr[j]));
                if (++j == 50) { j = 0; ++i; qv = b2f(qsr[i < 49 ? i : 49]); }
                pk[u2] = (uint)lo | ((uint)hi << 16);
            }
            uint4* dst = (uint4*)(Xs + nl * 136 + kc);
            #pragma unroll
            for (int m = 0; m < 4; ++m)
                dst[m] = make_uint4(pk[m*4], pk[m*4+1], pk[m*4+2], pk[m*4+3]);
        }
        __syncthreads();
        #pragma unroll
        for (int ks = 0; ks < 4; ++ks) {
            bf16x8 a = *(const bf16x8*)(Xs + (w * 16 + c) * 136 + ks * 32 + quad * 8);
            #pragma unroll
            for (int nt = 0; nt < 4; ++nt) {
                bf16x8 b = *(const bf16x8*)(Bs + (nt * 16 + c) * 136 + ks * 32 + quad * 8);
                acc[nt] = __builtin_amdgcn_mfma_f32_16x16x32_bf16(a, b, acc[nt], 0, 0, 0);
            }
        }
    }
    // epilogue: part[h][node][o]
    #pragma unroll
    for (int nt = 0; nt < 4; ++nt) {
        const int o = nt * 16 + c;
        #pragma unroll
        for (int r = 0; r < 4; ++r) {
            const int node = n0 + w * 16 + quad * 4 + r;
            if (node < NN)
                part[((size_t)h * NN + node) * 64 + o] = acc[nt][r];
        }
    }
}

// ---------- B: weighted neighbor sum + Wg matvec + ELU + rank head ----------
__global__ __launch_bounds__(256) void kB(const float* __restrict__ nb,
                                          const float* __restrict__ scores,
                                          const float* __restrict__ part,
                                          const float* __restrict__ bbil,
                                          const float* __restrict__ Wg,
                                          const float* __restrict__ g_bias,
                                          const float* __restrict__ Wr,
                                          const float* __restrict__ br,
                                          float* __restrict__ out) {
    __shared__ float Wgs[50 * 51];
    __shared__ float scs[256];
    __shared__ float tv[4][52];

    const int tid = threadIdx.x;
    const int n0 = blockIdx.x * 4;
    for (int idx = tid; idx < 2500; idx += 256) {
        int o = idx / 50, d = idx - o * 50;
        Wgs[o * 51 + d] = Wg[idx];
    }
    scs[tid] = scores[(size_t)n0 * 64 + tid];
    __syncthreads();

    const int w = tid >> 6, lane = tid & 63;
    const int n = n0 + w;
    if (lane < 25) {
        const int d2 = lane * 2;
        const float* base = nb + (size_t)n * 3150 + d2;
        const float* sw = &scs[w * 64];
        float t0 = 0.f, t1 = 0.f;
        #pragma unroll 9
        for (int k = 0; k < 63; ++k) {
            const float2 v = *(const float2*)(base + k * 50);
            t0 += sw[k] * v.x; t1 += sw[k] * v.y;
        }
        const float2 p0 = *(const float2*)(part + (size_t)n * 64 + d2);
        const float2 p1 = *(const float2*)(part + ((size_t)NN + n) * 64 + d2);
        tv[w][d2]     = t0 + sw[63] * (p0.x + p1.x + bbil[d2]);
        tv[w][d2 + 1] = t1 + sw[63] * (p0.y + p1.y + bbil[d2 + 1]);
    }
    __syncthreads();

    float p = 0.f;
    if (lane < 50) {
        float a = g_bias[lane];
        const float* wrow = &Wgs[lane * 51];
        const float* twv = &tv[w][0];
        #pragma unroll 10
        for (int d = 0; d < 50; ++d) a += wrow[d] * twv[d];
        const float f = a > 0.f ? a : (__expf(a) - 1.f);
        p = f * Wr[lane];
    }
    #pragma unroll
    for (int off = 32; off; off >>= 1) p += __shfl_down(p, off);
    if (lane == 0) out[n] = p + br[0];
}

extern "C" void kernel_launch(void* const* d_in, const int* in_sizes, int n_in,
                              void* d_out, int out_size, void* d_ws, size_t ws_size,
                              hipStream_t stream) {
    const float* q_   = (const float*)d_in[0];
    const float* ent  = (const float*)d_in[1];
    const float* nb   = (const float*)d_in[2];
    const float* scr  = (const float*)d_in[3];
    const float* Wp   = (const float*)d_in[4];
    const float* bp   = (const float*)d_in[5];
    const float* Wb   = (const float*)d_in[6];
    const float* bb   = (const float*)d_in[7];
    const float* Wg   = (const float*)d_in[8];
    const float* gb   = (const float*)d_in[9];
    const float* Wr   = (const float*)d_in[10];
    const float* br   = (const float*)d_in[11];
    float* out = (float*)d_out;

    ushort* WtT = (ushort*)d_ws;            // 64*2560 = 163840 ushorts
    ushort* WpB = WtT + 64 * 2560;          // 64*384  =  24576 ushorts
    float*  part = (float*)(WpB + 64 * 384);// 2*NN*64 floats (byte off 376832, 16B aligned)

    hipLaunchKernelGGL(kPrep, dim3(184),  dim3(256), 0, stream, Wb, Wp, WtT, WpB);
    hipLaunchKernelGGL(kMain, dim3(626),  dim3(256), 0, stream, q_, ent, bp, WpB, WtT, part);
    hipLaunchKernelGGL(kB,    dim3(5000), dim3(256), 0, stream, nb, scr, part, bb, Wg, gb, Wr, br, out);
}

// Round 4
// 437.998 us; speedup vs baseline: 2.0184x; 1.0382x over previous
//
#include <hip/hip_runtime.h>
#include <math.h>

#define NN 20000
typedef unsigned int uint;
typedef unsigned short ushort;
typedef __attribute__((ext_vector_type(8))) short bf16x8;
typedef __attribute__((ext_vector_type(4))) float f32x4;

union U8 { uint4 u; bf16x8 v; };

__device__ __forceinline__ ushort f2b(float x) {           // RNE
    uint u = __float_as_uint(x);
    return (ushort)((u + 0x7FFFu + ((u >> 16) & 1u)) >> 16);
}
__device__ __forceinline__ float b2f(ushort b) {
    return __uint_as_float(((uint)b) << 16);
}
// packed: two bf16 (in one uint) * scalar -> two bf16 (round-half-up)
__device__ __forceinline__ uint pkmul(uint e2, float qv) {
    float lo = __uint_as_float(e2 << 16) * qv;
    float hi = __uint_as_float(e2 & 0xFFFF0000u) * qv;
    uint ul = (__float_as_uint(lo) + 0x8000u) >> 16;
    uint uh = (__float_as_uint(hi) + 0x8000u) & 0xFFFF0000u;
    return ul | uh;
}

// ---------- Prep: padded bf16 weights ----------
// WtT2[o][k'=i*64+j] (64 x 3200), zero at o>=50 / j>=50.  WpB[d][e] (64 x 384).
__global__ __launch_bounds__(256) void kPrep(const float* __restrict__ Wbil,
                                             const float* __restrict__ Wp,
                                             ushort* __restrict__ WtT2,
                                             ushort* __restrict__ WpB) {
    const int stride = gridDim.x * 256;
    for (int idx = blockIdx.x * 256 + threadIdx.x; idx < 64 * 3200; idx += stride) {
        int o = idx / 3200, k = idx - o * 3200;
        int i = k >> 6, j = k & 63;
        WtT2[idx] = (o < 50 && j < 50) ? f2b(Wbil[o * 2500 + i * 50 + j]) : (ushort)0;
    }
    for (int idx = blockIdx.x * 256 + threadIdx.x; idx < 64 * 384; idx += stride) {
        int d = idx / 384, e = idx - d * 384;
        WpB[idx] = (d < 50 && e < 300) ? f2b(Wp[d * 300 + e]) : (ushort)0;
    }
}

// ---------- Main: fused ent-GEMM + bilinear-GEMM, register A-fragments ----------
// 64 nodes/block, split-K=2 (h=0: i<26 -> 13 tiles; h=1: i in [26,50) -> 12 tiles).
__global__ __launch_bounds__(256, 3) void kMain(
    const float* __restrict__ q,       // [N,50]
    const float* __restrict__ entity,  // [N,300]
    const float* __restrict__ bp,      // [50]
    const ushort* __restrict__ WpB,    // [64][384] bf16
    const ushort* __restrict__ WtT2,   // [64][3200] bf16
    float* __restrict__ part)          // [2][NN][64]
{
    __shared__ ushort qs[64 * 50];        // bf16 q tile [node][i]
    __shared__ ushort es[64 * 72];        // bf16 ent tile [node][d], stride 72 (144 B)
    __shared__ ushort Bs[2][64 * 144];    // B tiles [row][k], stride 144 (288 B)

    const int tid = threadIdx.x;
    const int h = blockIdx.x & 1;
    const int n0 = (blockIdx.x >> 1) * 64;
    const int w = tid >> 6, lane = tid & 63;
    const int c = lane & 15, quad = lane >> 4;
    const int nl = tid >> 2;              // staging row 0..63
    const int kc = (tid & 3) * 32;        // staging col chunk (ushorts)
    const int myrow = w * 16 + c;         // this lane's node row (0..63)

    // stage q tile as bf16
    for (int i = tid; i < 3200; i += 256) {
        int r = i / 50, d = i - r * 50;
        float v = (n0 + r < NN) ? q[(size_t)(n0 + r) * 50 + d] : 0.f;
        qs[i] = f2b(v);
    }

    // ---- phase 0: ent[64,64] = entity[64,384pad] @ WpB^T ----
    ushort* BsE = &Bs[0][0];
    ushort* BsW = &Bs[1][0];
    f32x4 accE[4] = {{0.f,0.f,0.f,0.f},{0.f,0.f,0.f,0.f},{0.f,0.f,0.f,0.f},{0.f,0.f,0.f,0.f}};
    for (int t = 0; t < 3; ++t) {
        const int e0 = t * 128;
        __syncthreads();
        {   // stage entity -> BsE (bf16)
            const int node = n0 + nl;
            uint pk[16];
            #pragma unroll
            for (int u8 = 0; u8 < 8; ++u8) {
                const int e = e0 + kc + u8 * 4;
                float4 v = make_float4(0.f, 0.f, 0.f, 0.f);
                if (node < NN && e < 300)
                    v = *(const float4*)(entity + (size_t)node * 300 + e);
                pk[u8 * 2]     = (uint)f2b(v.x) | ((uint)f2b(v.y) << 16);
                pk[u8 * 2 + 1] = (uint)f2b(v.z) | ((uint)f2b(v.w) << 16);
            }
            uint4* dst = (uint4*)(BsE + nl * 144 + kc);
            #pragma unroll
            for (int m = 0; m < 4; ++m)
                dst[m] = make_uint4(pk[m*4], pk[m*4+1], pk[m*4+2], pk[m*4+3]);
        }
        {   // stage WpB -> BsW
            const uint4* src = (const uint4*)(WpB + nl * 384 + e0 + kc);
            uint4 v0 = src[0], v1 = src[1], v2 = src[2], v3 = src[3];
            uint4* dst = (uint4*)(BsW + nl * 144 + kc);
            dst[0] = v0; dst[1] = v1; dst[2] = v2; dst[3] = v3;
        }
        __syncthreads();
        #pragma unroll
        for (int ks = 0; ks < 4; ++ks) {
            bf16x8 a = *(const bf16x8*)(BsE + myrow * 144 + ks * 32 + quad * 8);
            #pragma unroll
            for (int nt = 0; nt < 4; ++nt) {
                bf16x8 b = *(const bf16x8*)(BsW + (nt * 16 + c) * 144 + ks * 32 + quad * 8);
                accE[nt] = __builtin_amdgcn_mfma_f32_16x16x32_bf16(a, b, accE[nt], 0, 0, 0);
            }
        }
    }
    // es epilogue: D row = quad*4+r (wave-local rows w*16..+16), col = c + nt*16.
    // Full 64-wide rows written (zeros at d>=50) so A-slices read clean zeros.
    #pragma unroll
    for (int nt = 0; nt < 4; ++nt) {
        const int d = nt * 16 + c;
        const float bias = (d < 50) ? bp[d] : 0.f;
        #pragma unroll
        for (int r = 0; r < 4; ++r) {
            const int row = w * 16 + quad * 4 + r;
            es[row * 72 + d] = (d < 50) ? f2b(accE[nt][r] + bias) : (ushort)0;
        }
    }
    // preload this lane's two ent slices (same-wave data; compiler inserts lgkmcnt)
    const ushort* myes = es + myrow * 72;
    const uint4 es0 = *(const uint4*)(myes + quad * 8);
    const uint4 es1 = *(const uint4*)(myes + 32 + quad * 8);
    const ushort* qrow = qs + myrow * 50;

    // ---- phase 1: bilinear over k' = i*64+j ----
    const int kb0 = h ? 1664 : 0;
    const int ntiles = h ? 12 : 13;
    f32x4 acc[4] = {{0.f,0.f,0.f,0.f},{0.f,0.f,0.f,0.f},{0.f,0.f,0.f,0.f},{0.f,0.f,0.f,0.f}};

    __syncthreads();   // phase-0 Bs reads done before restage
    {   // stage tile 0 -> Bs[0]
        const uint4* src = (const uint4*)(WtT2 + nl * 3200 + kb0 + kc);
        uint4 v0 = src[0], v1 = src[1], v2 = src[2], v3 = src[3];
        uint4* dst = (uint4*)(&Bs[0][0] + nl * 144 + kc);
        dst[0] = v0; dst[1] = v1; dst[2] = v2; dst[3] = v3;
    }
    __syncthreads();

    for (int t = 0; t < ntiles; ++t) {
        // prefetch next W tile into registers
        uint4 p0, p1, p2, p3;
        if (t + 1 < ntiles) {
            const uint4* src = (const uint4*)(WtT2 + nl * 3200 + kb0 + (t + 1) * 128 + kc);
            p0 = src[0]; p1 = src[1]; p2 = src[2]; p3 = src[3];
        }
        const ushort* Bcur = &Bs[t & 1][0];
        const int i0 = (kb0 >> 6) + 2 * t;
        #pragma unroll
        for (int ip = 0; ip < 2; ++ip) {
            const float qv = b2f(qrow[i0 + ip]);
            #pragma unroll
            for (int hf = 0; hf < 2; ++hf) {
                const uint4 eu = hf ? es1 : es0;
                U8 ua;
                ua.u = make_uint4(pkmul(eu.x, qv), pkmul(eu.y, qv),
                                  pkmul(eu.z, qv), pkmul(eu.w, qv));
                const int ko = ip * 64 + hf * 32 + quad * 8;
                #pragma unroll
                for (int nt = 0; nt < 4; ++nt) {
                    bf16x8 b = *(const bf16x8*)(Bcur + (nt * 16 + c) * 144 + ko);
                    acc[nt] = __builtin_amdgcn_mfma_f32_16x16x32_bf16(ua.v, b, acc[nt], 0, 0, 0);
                }
            }
        }
        if (t + 1 < ntiles) {
            uint4* dst = (uint4*)(&Bs[(t + 1) & 1][0] + nl * 144 + kc);
            dst[0] = p0; dst[1] = p1; dst[2] = p2; dst[3] = p3;
        }
        __syncthreads();
    }

    // epilogue: part[h][node][o]
    #pragma unroll
    for (int nt = 0; nt < 4; ++nt) {
        const int o = nt * 16 + c;
        #pragma unroll
        for (int r = 0; r < 4; ++r) {
            const int node = n0 + w * 16 + quad * 4 + r;
            if (node < NN)
                part[((size_t)h * NN + node) * 64 + o] = acc[nt][r];
        }
    }
}

// ---------- B: weighted neighbor sum + Wg matvec + ELU + rank head ----------
__global__ __launch_bounds__(256) void kB(const float* __restrict__ nb,
                                          const float* __restrict__ scores,
                                          const float* __restrict__ part,
                                          const float* __restrict__ bbil,
                                          const float* __restrict__ Wg,
                                          const float* __restrict__ g_bias,
                                          const float* __restrict__ Wr,
                                          const float* __restrict__ br,
                                          float* __restrict__ out) {
    __shared__ float Wgs[50 * 51];
    __shared__ float scs[256];
    __shared__ float tv[4][52];

    const int tid = threadIdx.x;
    const int n0 = blockIdx.x * 4;
    for (int idx = tid; idx < 2500; idx += 256) {
        int o = idx / 50, d = idx - o * 50;
        Wgs[o * 51 + d] = Wg[idx];
    }
    scs[tid] = scores[(size_t)n0 * 64 + tid];
    __syncthreads();

    const int w = tid >> 6, lane = tid & 63;
    const int n = n0 + w;
    if (lane < 25) {
        const int d2 = lane * 2;
        const float* base = nb + (size_t)n * 3150 + d2;
        const float* sw = &scs[w * 64];
        float t0 = 0.f, t1 = 0.f;
        #pragma unroll 9
        for (int k = 0; k < 63; ++k) {
            const float2 v = *(const float2*)(base + k * 50);
            t0 += sw[k] * v.x; t1 += sw[k] * v.y;
        }
        const float2 p0 = *(const float2*)(part + (size_t)n * 64 + d2);
        const float2 p1 = *(const float2*)(part + ((size_t)NN + n) * 64 + d2);
        tv[w][d2]     = t0 + sw[63] * (p0.x + p1.x + bbil[d2]);
        tv[w][d2 + 1] = t1 + sw[63] * (p0.y + p1.y + bbil[d2 + 1]);
    }
    __syncthreads();

    float p = 0.f;
    if (lane < 50) {
        float a = g_bias[lane];
        const float* wrow = &Wgs[lane * 51];
        const float* twv = &tv[w][0];
        #pragma unroll 10
        for (int d = 0; d < 50; ++d) a += wrow[d] * twv[d];
        const float f = a > 0.f ? a : (__expf(a) - 1.f);
        p = f * Wr[lane];
    }
    #pragma unroll
    for (int off = 32; off; off >>= 1) p += __shfl_down(p, off);
    if (lane == 0) out[n] = p + br[0];
}

extern "C" void kernel_launch(void* const* d_in, const int* in_sizes, int n_in,
                              void* d_out, int out_size, void* d_ws, size_t ws_size,
                              hipStream_t stream) {
    const float* q_   = (const float*)d_in[0];
    const float* ent  = (const float*)d_in[1];
    const float* nb   = (const float*)d_in[2];
    const float* scr  = (const float*)d_in[3];
    const float* Wp   = (const float*)d_in[4];
    const float* bp   = (const float*)d_in[5];
    const float* Wb   = (const float*)d_in[6];
    const float* bb   = (const float*)d_in[7];
    const float* Wg   = (const float*)d_in[8];
    const float* gb   = (const float*)d_in[9];
    const float* Wr   = (const float*)d_in[10];
    const float* br   = (const float*)d_in[11];
    float* out = (float*)d_out;

    ushort* WtT2 = (ushort*)d_ws;              // 64*3200 = 204800 ushorts
    ushort* WpB  = WtT2 + 64 * 3200;           // 64*384  =  24576 ushorts
    float*  part = (float*)(WpB + 64 * 384);   // byte off 458752 (16B aligned), 2*NN*64 f32

    hipLaunchKernelGGL(kPrep, dim3(256),  dim3(256), 0, stream, Wb, Wp, WtT2, WpB);
    hipLaunchKernelGGL(kMain, dim3(626),  dim3(256), 0, stream, q_, ent, bp, WpB, WtT2, part);
    hipLaunchKernelGGL(kB,    dim3(5000), dim3(256), 0, stream, nb, scr, part, bb, Wg, gb, Wr, br, out);
}